// Round 1
// baseline (570.493 us; speedup 1.0000x reference)
//
#include <hip/hip_runtime.h>
#include <hip/hip_cooperative_groups.h>

namespace cg = cooperative_groups;

// ---------- types ----------
typedef __attribute__((ext_vector_type(8))) short sh8;    // 8 x bf16 (as raw shorts)
typedef __attribute__((ext_vector_type(4))) float fl4;    // MFMA accumulator

__device__ __forceinline__ unsigned short f2bf(float f) {
    unsigned int u = __float_as_uint(f);
    unsigned int r = (u + 0x7fffu + ((u >> 16) & 1u)) >> 16;   // round-to-nearest-even
    return (unsigned short)r;
}

// async global->LDS, 16 B per lane. LDS dest is wave-uniform base + lane*16.
#define GLDS16(gp, lp) __builtin_amdgcn_global_load_lds( \
    (const __attribute__((address_space(1))) void*)(gp), \
    (__attribute__((address_space(3))) void*)(lp), 16, 0, 0)

// ---------- constants ----------
#define NROWS   8192
#define D_IN    512
#define D_HID   1024
#define D_OUT   512
#define NNEIGH  16

// ---------------------------------------------------------------------------
// prep unit b in [0,1536): same work decomposition as the previous 3-kernel
// version's prep grid:
//   [0,512)    : hidden = x + mean(x[row+1..row+16 mod N]) -> bf16 (16 rows)
//   [512,1024) : W1 [512x1024] fp32 -> W1t bf16 [1024x512] (B^T form)
//   [1024,1536): W2 [1024x512] fp32 -> W2t bf16 [512x1024]
// ---------------------------------------------------------------------------
__device__ __forceinline__ void prep_unit(
    int b,
    const float* __restrict__ x,
    const int* __restrict__ mask_w,
    unsigned short* __restrict__ hB,
    const float* __restrict__ W1, unsigned short* __restrict__ W1t,
    const float* __restrict__ W2, unsigned short* __restrict__ W2t,
    float (*tile)[33], int* okrow, int* idxs, int* cnt)
{
    const int tid = threadIdx.x;

    if (b >= 512) {
        // ---------------- transpose+cast paths ----------------
        const float* in; unsigned short* out; int R, C, c0, r0;
        if (b < 1024) {                  // W1: R=512, C=1024, grid (32 x 16)
            const int i = b - 512;
            in = W1; out = W1t; R = D_IN; C = D_HID;
            c0 = (i & 31) * 32; r0 = (i >> 5) * 32;
        } else {                         // W2: R=1024, C=512, grid (16 x 32)
            const int i = b - 1024;
            in = W2; out = W2t; R = D_HID; C = D_OUT;
            c0 = (i & 15) * 32; r0 = (i >> 4) * 32;
        }
        const int tx = tid & 31, ty = tid >> 5;
        #pragma unroll
        for (int k = 0; k < 4; k++)
            tile[ty + 8 * k][tx] = in[(size_t)(r0 + ty + 8 * k) * C + c0 + tx];
        __syncthreads();
        #pragma unroll
        for (int k = 0; k < 4; k++)
            out[(size_t)(c0 + ty + 8 * k) * R + r0 + tx] = f2bf(tile[tx][ty + 8 * k]);
        __syncthreads();                 // tile reuse safety across units
        return;
    }

    // ---------------- neighbor-mean + residual path ----------------
    const int r0 = b * 16;
    const bool i32mode = (mask_w[1] == 1);

    if (tid < 16) okrow[tid] = 1;
    __syncthreads();
    {   // verify: thread (rl,k) checks mask[row rl][col row+1+k]
        const int rl = tid >> 4, k = tid & 15;
        const int row = r0 + rl;
        int c = row + 1 + k; if (c >= NROWS) c -= NROWS;
        int set = i32mode ? (mask_w[(size_t)row * NROWS + c] != 0)
                          : (((const unsigned char*)mask_w)[(size_t)row * NROWS + c] != 0);
        if (!set) atomicAnd(&okrow[rl], 0);
    }
    __syncthreads();
    bool allok = true;
    #pragma unroll
    for (int i = 0; i < 16; i++) allok &= (okrow[i] != 0);

    const float2* X = (const float2*)x;                 // row stride 256 float2
    auto rowp = [&](int r) -> const float2* {
        int rr = (r >= NROWS) ? r - NROWS : r;
        return X + (size_t)rr * (D_IN / 2);
    };

    if (allok) {
        float wx = 0.f, wy = 0.f;                       // window sum rows r0+1..r0+16
        #pragma unroll 4
        for (int j = 1; j <= 16; j++) {
            const float2 v = rowp(r0 + j)[tid];
            wx += v.x; wy += v.y;
        }
        float2 xr = rowp(r0)[tid];
        #pragma unroll 2
        for (int r = 0; r < 16; r++) {
            const int row = r0 + r;
            const float2 sub = rowp(row + 1)[tid];      // leaves window; = x[row+1]
            const float2 add = rowp(row + 17)[tid];     // enters window
            ushort2 o;
            o.x = f2bf(xr.x + wx * (1.f / 16.f));
            o.y = f2bf(xr.y + wy * (1.f / 16.f));
            *((ushort2*)(hB + (size_t)row * D_IN) + tid) = o;
            wx += add.x - sub.x; wy += add.y - sub.y;
            xr = sub;                                   // x[row+1] is next row's x
        }
    } else {
        // robustness only; not expected to execute (branch is block-uniform)
        for (int r = 0; r < 16; r++) {
            const int row = r0 + r;
            if (tid == 0) *cnt = 0;
            if (tid < 64) idxs[tid] = row;
            __syncthreads();
            for (int j = 0; j < NROWS / 256; j++) {
                int c = tid * (NROWS / 256) + j;
                int set = i32mode ? (mask_w[(size_t)row * NROWS + c] != 0)
                                  : (((const unsigned char*)mask_w)[(size_t)row * NROWS + c] != 0);
                if (set) { int q = atomicAdd(cnt, 1); if (q < 64) idxs[q] = c; }
            }
            __syncthreads();
            float sx = 0.f, sy = 0.f;
            for (int k = 0; k < NNEIGH; k++) {
                int idx = idxs[k];
                idx = (idx < 0) ? 0 : ((idx > NROWS - 1) ? NROWS - 1 : idx);
                const float2 v = X[(size_t)idx * (D_IN / 2) + tid];
                sx += v.x; sy += v.y;
            }
            const float2 xv = X[(size_t)row * (D_IN / 2) + tid];
            ushort2 o;
            o.x = f2bf(xv.x + sx * (1.f / 16.f));
            o.y = f2bf(xv.y + sy * (1.f / 16.f));
            *((ushort2*)(hB + (size_t)row * D_IN) + tid) = o;
            __syncthreads();
        }
    }
    __syncthreads();                                    // okrow reuse safety
}

// ---------------------------------------------------------------------------
// GEMM unit: bf16 MFMA, A [M x K] rm, Bt [N x K] rm (B^T), C = A*B + bias,
// optional ReLU, bf16 or fp32 out. 4 waves as WGM x WGN, wave tile
// (TM*16)x(TN*16), block tile BM x BN, BK=64. global_load_lds dwordx4
// staging; unpadded LDS with XOR-on-k swizzle (kv ^ ((row&7)<<3), 16B
// chunks) -> 2-way bank aliasing = free (m136). Body identical to the
// previously-verified gemm_bt; blockIdx replaced by (bx,by), LDS passed in.
// ---------------------------------------------------------------------------
template<int WGM, int WGN, int TM, int TN, bool RELU, bool OUT_BF16>
__device__ __forceinline__ void gemm_unit(
    int bx, int by,
    const unsigned short* __restrict__ A,
    const unsigned short* __restrict__ Bt,
    const float* __restrict__ bias,
    void* __restrict__ Cout,
    int M, int N, int K,
    unsigned short* __restrict__ As,
    unsigned short* __restrict__ Bs)
{
    constexpr int BM = WGM * TM * 16;
    constexpr int BN = WGN * TN * 16;
    constexpr int ASLOTS = BM * 64 / 2048;
    constexpr int BSLOTS = BN * 64 / 2048;

    const int tid  = threadIdx.x;
    const long m0  = (long)by * BM;
    const long n0  = (long)bx * BN;
    const int wave = tid >> 6, lane = tid & 63;
    const int wm = (wave % WGM) * (TM * 16), wn = (wave / WGM) * (TN * 16);
    const int lm = lane & 15, q8 = (lane >> 4) * 8;

    fl4 acc[TM][TN] = {};

    for (int kt = 0; kt < K; kt += 64) {
        #pragma unroll
        for (int s = 0; s < ASLOTS; s++) {
            const int L = tid * 8 + s * 2048;
            const int row = L >> 6, kv = (L & 63) ^ ((row & 7) << 3);
            GLDS16(&A[(m0 + row) * K + kt + kv], &As[L]);
        }
        #pragma unroll
        for (int s = 0; s < BSLOTS; s++) {
            const int L = tid * 8 + s * 2048;
            const int row = L >> 6, kv = (L & 63) ^ ((row & 7) << 3);
            GLDS16(&Bt[(n0 + row) * K + kt + kv], &Bs[L]);
        }
        __syncthreads();

        #pragma unroll
        for (int ks = 0; ks < 2; ks++) {
            const int klog = ks * 32 + q8;
            sh8 af[TM], bf_[TN];
            #pragma unroll
            for (int t = 0; t < TM; t++) {
                const int ra = wm + t * 16 + lm;
                af[t] = *(const sh8*)(&As[ra * 64 + (klog ^ ((ra & 7) << 3))]);
            }
            #pragma unroll
            for (int t = 0; t < TN; t++) {
                const int rb = wn + t * 16 + lm;
                bf_[t] = *(const sh8*)(&Bs[rb * 64 + (klog ^ ((rb & 7) << 3))]);
            }
            #pragma unroll
            for (int tm = 0; tm < TM; tm++)
                #pragma unroll
                for (int tn = 0; tn < TN; tn++)
                    acc[tm][tn] = __builtin_amdgcn_mfma_f32_16x16x32_bf16(
                        af[tm], bf_[tn], acc[tm][tn], 0, 0, 0);
        }
        __syncthreads();
    }

    // epilogue: C/D layout col=lane&15, row=(lane>>4)*4+reg
    const int rq = (lane >> 4) * 4;
    #pragma unroll
    for (int tm = 0; tm < TM; tm++) {
        #pragma unroll
        for (int tn = 0; tn < TN; tn++) {
            const long col = n0 + wn + tn * 16 + lm;
            const float bv = bias[col];
            #pragma unroll
            for (int r = 0; r < 4; r++) {
                const long row = m0 + wm + tm * 16 + rq + r;
                float v = acc[tm][tn][r] + bv;
                if (RELU) v = fmaxf(v, 0.f);
                if (OUT_BF16) ((unsigned short*)Cout)[row * N + col] = f2bf(v);
                else          ((float*)Cout)[row * N + col] = v;
            }
        }
    }
}

// ---------------------------------------------------------------------------
// fused cooperative kernel: prep -> grid.sync -> gemm1 -> grid.sync -> gemm2.
// grid 512 x 256thr; LDS ~37 KB + VGPR<=256 (launch_bounds 256,2) guarantees
// 2 blocks/CU co-residency (512 = 2 x 256 CUs) for the cooperative launch.
// ---------------------------------------------------------------------------
__global__ __launch_bounds__(256, 2) void fused(
    const float* __restrict__ x,
    const int* __restrict__ mask_w,
    unsigned short* __restrict__ hiddenB,
    const float* __restrict__ W1, unsigned short* __restrict__ W1t,
    const float* __restrict__ W2, unsigned short* __restrict__ W2t,
    const float* __restrict__ b1,
    unsigned short* __restrict__ h,
    const float* __restrict__ b2,
    float* __restrict__ out)
{
    __shared__ unsigned short As[128 * 64];   // 16 KB (max of both gemm phases)
    __shared__ unsigned short Bs[128 * 64];   // 16 KB
    __shared__ float tile[32][33];            // prep transpose staging
    __shared__ int okrow[16];
    __shared__ int idxs[64];
    __shared__ int cnt;

    cg::grid_group grid = cg::this_grid();

    // phase 1: all pre-GEMM work (1536 units over gridDim blocks)
    for (int u = blockIdx.x; u < 1536; u += gridDim.x)
        prep_unit(u, x, mask_w, hiddenB, W1, W1t, W2, W2t, tile, okrow, idxs, &cnt);

    grid.sync();

    // phase 2: gemm1  h = relu(hiddenB @ W1 + b1), 128x128 tiles, vgrid (8,64)
    for (int vb = blockIdx.x; vb < 512; vb += gridDim.x)
        gemm_unit<2, 2, 4, 4, true, true>(vb & 7, vb >> 3,
            hiddenB, W1t, b1, h, NROWS, D_HID, D_IN, As, Bs);

    grid.sync();

    // phase 3: gemm2  out = h @ W2 + b2, 64x128 tiles, vgrid (4,128)
    for (int vb = blockIdx.x; vb < 512; vb += gridDim.x)
        gemm_unit<1, 4, 4, 2, false, false>(vb & 3, vb >> 2,
            h, W2t, b2, out, NROWS, D_OUT, D_HID, As, Bs);
}

// ---------------------------------------------------------------------------
// non-cooperative fallback wrappers (identical to previous 3-kernel version)
// ---------------------------------------------------------------------------
__global__ __launch_bounds__(256) void prep(
    const float* __restrict__ x,
    const int* __restrict__ mask_w,
    unsigned short* __restrict__ hB,
    const float* __restrict__ W1, unsigned short* __restrict__ W1t,
    const float* __restrict__ W2, unsigned short* __restrict__ W2t)
{
    __shared__ float tile[32][33];
    __shared__ int okrow[16];
    __shared__ int idxs[64];
    __shared__ int cnt;
    prep_unit(blockIdx.x, x, mask_w, hB, W1, W1t, W2, W2t, tile, okrow, idxs, &cnt);
}

template<int WGM, int WGN, int TM, int TN, bool RELU, bool OUT_BF16>
__global__ __launch_bounds__(256) void gemm_bt(
    const unsigned short* __restrict__ A,
    const unsigned short* __restrict__ Bt,
    const float* __restrict__ bias,
    void* __restrict__ Cout,
    int M, int N, int K)
{
    constexpr int BM = WGM * TM * 16;
    constexpr int BN = WGN * TN * 16;
    __shared__ unsigned short As[BM * 64];
    __shared__ unsigned short Bs[BN * 64];
    gemm_unit<WGM, WGN, TM, TN, RELU, OUT_BF16>(blockIdx.x, blockIdx.y,
        A, Bt, bias, Cout, M, N, K, As, Bs);
}

// ---------------------------------------------------------------------------
extern "C" void kernel_launch(void* const* d_in, const int* in_sizes, int n_in,
                              void* d_out, int out_size, void* d_ws, size_t ws_size,
                              hipStream_t stream)
{
    const float* x     = (const float*)d_in[0];
    const int*   fmask = (const int*)d_in[2];
    const float* W1    = (const float*)d_in[3];
    const float* b1    = (const float*)d_in[4];
    const float* W2    = (const float*)d_in[5];
    const float* b2    = (const float*)d_in[6];
    float*       out   = (float*)d_out;

    // Scratch (bf16 elts): hiddenB 4Mi | W1t 512Ki | W2t 512Ki | h 8Mi = 26 MB.
    const size_t needElts = (size_t)NROWS * D_IN + (size_t)D_HID * D_IN
                          + (size_t)D_OUT * D_HID + (size_t)NROWS * D_HID;
    unsigned short* base = (ws_size >= needElts * sizeof(unsigned short))
                         ? (unsigned short*)d_ws
                         : (unsigned short*)d_in[1];

    unsigned short* hiddenB = base;
    unsigned short* W1t     = hiddenB + (size_t)NROWS * D_IN;
    unsigned short* W2t     = W1t + (size_t)D_HID * D_IN;
    unsigned short* h       = W2t + (size_t)D_OUT * D_HID;

    void* args[] = { (void*)&x, (void*)&fmask, (void*)&hiddenB,
                     (void*)&W1, (void*)&W1t, (void*)&W2, (void*)&W2t,
                     (void*)&b1, (void*)&h, (void*)&b2, (void*)&out };

    hipError_t e = hipLaunchCooperativeKernel(
        reinterpret_cast<const void*>(&fused),
        dim3(512), dim3(256), args, 0, stream);

    if (e != hipSuccess) {
        (void)hipGetLastError();   // clear sticky error, use classic 3-launch path
        prep<<<1536, 256, 0, stream>>>(x, fmask, hiddenB, W1, W1t, W2, W2t);
        gemm_bt<2, 2, 4, 4, true, true><<<dim3(D_HID / 128, NROWS / 128), 256, 0, stream>>>(
            hiddenB, W1t, b1, h, NROWS, D_HID, D_IN);
        gemm_bt<1, 4, 4, 2, false, false><<<dim3(D_OUT / 128, NROWS / 64), 256, 0, stream>>>(
            h, W2t, b2, out, NROWS, D_OUT, D_HID);
    }
}

// Round 2
// 451.594 us; speedup vs baseline: 1.2633x; 1.2633x over previous
//
#include <hip/hip_runtime.h>

// ---------- types ----------
typedef __attribute__((ext_vector_type(8))) short sh8;    // 8 x bf16 (as raw shorts)
typedef __attribute__((ext_vector_type(4))) float fl4;    // MFMA accumulator

__device__ __forceinline__ unsigned short f2bf(float f) {
    unsigned int u = __float_as_uint(f);
    unsigned int r = (u + 0x7fffu + ((u >> 16) & 1u)) >> 16;   // round-to-nearest-even
    return (unsigned short)r;
}

// async global->LDS, 16 B per lane. LDS dest is wave-uniform base + lane*16.
#define GLDS16(gp, lp) __builtin_amdgcn_global_load_lds( \
    (const __attribute__((address_space(1))) void*)(gp), \
    (__attribute__((address_space(3))) void*)(lp), 16, 0, 0)

// ---------- constants ----------
#define NROWS   8192
#define D_IN    512
#define D_HID   1024
#define D_OUT   512
#define NNEIGH  16

// ---------------------------------------------------------------------------
// prep kernel: ONE launch does all pre-GEMM work (identical to the verified
// 449.5 µs version):
//   blocks [0,512)    : hidden = x + mean(x[row+1..row+16 mod N]) -> bf16
//   blocks [512,1024) : W1 [512x1024] fp32 -> W1t bf16 [1024x512] (B^T form)
//   blocks [1024,1536): W2 [1024x512] fp32 -> W2t bf16 [512x1024]
// ---------------------------------------------------------------------------
__global__ __launch_bounds__(256) void prep(
    const float* __restrict__ x,
    const int* __restrict__ mask_w,
    unsigned short* __restrict__ hB,
    const float* __restrict__ W1, unsigned short* __restrict__ W1t,
    const float* __restrict__ W2, unsigned short* __restrict__ W2t)
{
    const int b   = blockIdx.x;
    const int tid = threadIdx.x;

    __shared__ float tile[32][33];       // transpose staging
    __shared__ int okrow[16];
    __shared__ int idxs[64];
    __shared__ int cnt;

    if (b >= 512) {
        // ---------------- transpose+cast paths ----------------
        const float* in; unsigned short* out; int R, C, c0, r0;
        if (b < 1024) {                  // W1: R=512, C=1024, grid (32 x 16)
            const int i = b - 512;
            in = W1; out = W1t; R = D_IN; C = D_HID;
            c0 = (i & 31) * 32; r0 = (i >> 5) * 32;
        } else {                         // W2: R=1024, C=512, grid (16 x 32)
            const int i = b - 1024;
            in = W2; out = W2t; R = D_HID; C = D_OUT;
            c0 = (i & 15) * 32; r0 = (i >> 4) * 32;
        }
        const int tx = tid & 31, ty = tid >> 5;
        #pragma unroll
        for (int k = 0; k < 4; k++)
            tile[ty + 8 * k][tx] = in[(size_t)(r0 + ty + 8 * k) * C + c0 + tx];
        __syncthreads();
        #pragma unroll
        for (int k = 0; k < 4; k++)
            out[(size_t)(c0 + ty + 8 * k) * R + r0 + tx] = f2bf(tile[tx][ty + 8 * k]);
        return;
    }

    // ---------------- neighbor-mean + residual path ----------------
    const int r0 = b * 16;
    const bool i32mode = (mask_w[1] == 1);

    if (tid < 16) okrow[tid] = 1;
    __syncthreads();
    {   // verify: thread (rl,k) checks mask[row rl][col row+1+k]
        const int rl = tid >> 4, k = tid & 15;
        const int row = r0 + rl;
        int c = row + 1 + k; if (c >= NROWS) c -= NROWS;
        int set = i32mode ? (mask_w[(size_t)row * NROWS + c] != 0)
                          : (((const unsigned char*)mask_w)[(size_t)row * NROWS + c] != 0);
        if (!set) atomicAnd(&okrow[rl], 0);
    }
    __syncthreads();
    bool allok = true;
    #pragma unroll
    for (int i = 0; i < 16; i++) allok &= (okrow[i] != 0);

    const float2* X = (const float2*)x;                 // row stride 256 float2
    auto rowp = [&](int r) -> const float2* {
        int rr = (r >= NROWS) ? r - NROWS : r;
        return X + (size_t)rr * (D_IN / 2);
    };

    if (allok) {
        float wx = 0.f, wy = 0.f;                       // window sum rows r0+1..r0+16
        #pragma unroll 4
        for (int j = 1; j <= 16; j++) {
            const float2 v = rowp(r0 + j)[tid];
            wx += v.x; wy += v.y;
        }
        float2 xr = rowp(r0)[tid];
        #pragma unroll 2
        for (int r = 0; r < 16; r++) {
            const int row = r0 + r;
            const float2 sub = rowp(row + 1)[tid];      // leaves window; = x[row+1]
            const float2 add = rowp(row + 17)[tid];     // enters window
            ushort2 o;
            o.x = f2bf(xr.x + wx * (1.f / 16.f));
            o.y = f2bf(xr.y + wy * (1.f / 16.f));
            *((ushort2*)(hB + (size_t)row * D_IN) + tid) = o;
            wx += add.x - sub.x; wy += add.y - sub.y;
            xr = sub;                                   // x[row+1] is next row's x
        }
    } else {
        // robustness only; not expected to execute (branch is block-uniform)
        for (int r = 0; r < 16; r++) {
            const int row = r0 + r;
            if (tid == 0) cnt = 0;
            if (tid < 64) idxs[tid] = row;
            __syncthreads();
            for (int j = 0; j < NROWS / 256; j++) {
                int c = tid * (NROWS / 256) + j;
                int set = i32mode ? (mask_w[(size_t)row * NROWS + c] != 0)
                                  : (((const unsigned char*)mask_w)[(size_t)row * NROWS + c] != 0);
                if (set) { int q = atomicAdd(&cnt, 1); if (q < 64) idxs[q] = c; }
            }
            __syncthreads();
            float sx = 0.f, sy = 0.f;
            for (int k = 0; k < NNEIGH; k++) {
                int idx = idxs[k];
                idx = (idx < 0) ? 0 : ((idx > NROWS - 1) ? NROWS - 1 : idx);
                const float2 v = X[(size_t)idx * (D_IN / 2) + tid];
                sx += v.x; sy += v.y;
            }
            const float2 xv = X[(size_t)row * (D_IN / 2) + tid];
            ushort2 o;
            o.x = f2bf(xv.x + sx * (1.f / 16.f));
            o.y = f2bf(xv.y + sy * (1.f / 16.f));
            *((ushort2*)(hB + (size_t)row * D_IN) + tid) = o;
            __syncthreads();
        }
    }
}

// ---------------------------------------------------------------------------
// GEMM: bf16 MFMA, A [M x K] rm, Bt [N x K] rm (B^T), C = A*B + bias,
// optional ReLU, bf16 or fp32 out. 4 waves as WGM x WGN, wave tile
// (TM*16)x(TN*16), block tile BM x BN, BK=64. global_load_lds dwordx4
// staging; unpadded LDS with XOR-on-k swizzle (kv ^ ((row&7)<<3), 16B
// chunks) -> 2-way bank aliasing = free (m136).
//
// NEW vs the 449.5 µs version: 1-D grid of 512 blocks + XCD-chunked
// bijective swizzle (T1, m204 form; nwg=512, 512%8==0 so q=64, r=0):
//   swz = (orig & 7)*64 + (orig >> 3);  bx = swz % NBX; by = swz / NBX;
// Each XCD then owns a contiguous 64-tile slab (8 row-panels x all cols
// for gemm1) -> A panels + the full W matrix become L2-resident instead
// of being re-fetched into all 8 XCD L2s. Pure block->tile permutation;
// no correctness dependence on the mapping (speed heuristic only).
// ---------------------------------------------------------------------------
template<int WGM, int WGN, int TM, int TN, bool RELU, bool OUT_BF16, int NBX>
__global__ __launch_bounds__(256) void gemm_bt(
    const unsigned short* __restrict__ A,
    const unsigned short* __restrict__ Bt,
    const float* __restrict__ bias,
    void* __restrict__ Cout,
    int M, int N, int K)
{
    constexpr int BM = WGM * TM * 16;
    constexpr int BN = WGN * TN * 16;
    constexpr int ASLOTS = BM * 64 / 2048;
    constexpr int BSLOTS = BN * 64 / 2048;
    __shared__ unsigned short As[BM * 64];
    __shared__ unsigned short Bs[BN * 64];

    // XCD-chunked swizzle (8 XCDs, grid fixed at 512 blocks)
    const int orig = blockIdx.x;
    const int swz  = (orig & 7) * 64 + (orig >> 3);
    const int bx   = swz % NBX;
    const int by   = swz / NBX;

    const int tid  = threadIdx.x;
    const long m0  = (long)by * BM;
    const long n0  = (long)bx * BN;
    const int wave = tid >> 6, lane = tid & 63;
    const int wm = (wave % WGM) * (TM * 16), wn = (wave / WGM) * (TN * 16);
    const int lm = lane & 15, q8 = (lane >> 4) * 8;

    fl4 acc[TM][TN] = {};

    for (int kt = 0; kt < K; kt += 64) {
        #pragma unroll
        for (int s = 0; s < ASLOTS; s++) {
            const int L = tid * 8 + s * 2048;
            const int row = L >> 6, kv = (L & 63) ^ ((row & 7) << 3);
            GLDS16(&A[(m0 + row) * K + kt + kv], &As[L]);
        }
        #pragma unroll
        for (int s = 0; s < BSLOTS; s++) {
            const int L = tid * 8 + s * 2048;
            const int row = L >> 6, kv = (L & 63) ^ ((row & 7) << 3);
            GLDS16(&Bt[(n0 + row) * K + kt + kv], &Bs[L]);
        }
        __syncthreads();

        #pragma unroll
        for (int ks = 0; ks < 2; ks++) {
            const int klog = ks * 32 + q8;
            sh8 af[TM], bf_[TN];
            #pragma unroll
            for (int t = 0; t < TM; t++) {
                const int ra = wm + t * 16 + lm;
                af[t] = *(const sh8*)(&As[ra * 64 + (klog ^ ((ra & 7) << 3))]);
            }
            #pragma unroll
            for (int t = 0; t < TN; t++) {
                const int rb = wn + t * 16 + lm;
                bf_[t] = *(const sh8*)(&Bs[rb * 64 + (klog ^ ((rb & 7) << 3))]);
            }
            #pragma unroll
            for (int tm = 0; tm < TM; tm++)
                #pragma unroll
                for (int tn = 0; tn < TN; tn++)
                    acc[tm][tn] = __builtin_amdgcn_mfma_f32_16x16x32_bf16(
                        af[tm], bf_[tn], acc[tm][tn], 0, 0, 0);
        }
        __syncthreads();
    }

    // epilogue: C/D layout col=lane&15, row=(lane>>4)*4+reg
    const int rq = (lane >> 4) * 4;
    #pragma unroll
    for (int tm = 0; tm < TM; tm++) {
        #pragma unroll
        for (int tn = 0; tn < TN; tn++) {
            const long col = n0 + wn + tn * 16 + lm;
            const float bv = bias[col];
            #pragma unroll
            for (int r = 0; r < 4; r++) {
                const long row = m0 + wm + tm * 16 + rq + r;
                float v = acc[tm][tn][r] + bv;
                if (RELU) v = fmaxf(v, 0.f);
                if (OUT_BF16) ((unsigned short*)Cout)[row * N + col] = f2bf(v);
                else          ((float*)Cout)[row * N + col] = v;
            }
        }
    }
}

// ---------------------------------------------------------------------------
extern "C" void kernel_launch(void* const* d_in, const int* in_sizes, int n_in,
                              void* d_out, int out_size, void* d_ws, size_t ws_size,
                              hipStream_t stream)
{
    const float* x     = (const float*)d_in[0];
    const int*   fmask = (const int*)d_in[2];
    const float* W1    = (const float*)d_in[3];
    const float* b1    = (const float*)d_in[4];
    const float* W2    = (const float*)d_in[5];
    const float* b2    = (const float*)d_in[6];
    float*       out   = (float*)d_out;

    // Scratch (bf16 elts): hiddenB 4Mi | W1t 512Ki | W2t 512Ki | h 8Mi = 26 MB.
    const size_t needElts = (size_t)NROWS * D_IN + (size_t)D_HID * D_IN
                          + (size_t)D_OUT * D_HID + (size_t)NROWS * D_HID;
    unsigned short* base = (ws_size >= needElts * sizeof(unsigned short))
                         ? (unsigned short*)d_ws
                         : (unsigned short*)d_in[1];

    unsigned short* hiddenB = base;
    unsigned short* W1t     = hiddenB + (size_t)NROWS * D_IN;
    unsigned short* W2t     = W1t + (size_t)D_HID * D_IN;
    unsigned short* h       = W2t + (size_t)D_OUT * D_HID;

    // one prep launch: neigh (512 blocks) + W1 transpose (512) + W2 transpose (512)
    prep<<<1536, 256, 0, stream>>>(x, fmask, hiddenB, W1, W1t, W2, W2t);
    // gemm1: 128x128 tile, 512 blocks (virtual grid 8 x 64), XCD-swizzled
    gemm_bt<2, 2, 4, 4, true, true, 8><<<512, 256, 0, stream>>>(
        hiddenB, W1t, b1, h, NROWS, D_HID, D_IN);
    // gemm2: 64x128 tile, 512 blocks (virtual grid 4 x 128), XCD-swizzled
    gemm_bt<1, 4, 4, 2, false, false, 4><<<512, 256, 0, stream>>>(
        h, W2t, b2, out, NROWS, D_OUT, D_HID);
}